// Round 19
// baseline (321.206 us; speedup 1.0000x reference)
//
#include <hip/hip_runtime.h>
#include <hip/hip_bf16.h>
#include <cstdint>
#include <cstddef>

typedef __attribute__((ext_vector_type(8))) short bf16x8;
typedef __attribute__((ext_vector_type(4))) float f32x4;

#define PI2F 6.283185307179586f

__device__ __forceinline__ float bf2f(unsigned short u) {
  union { float f; uint32_t i; } x; x.i = ((uint32_t)u) << 16; return x.f;
}
__device__ __forceinline__ unsigned short f2bf(float f) {
  union { float f; uint32_t i; } x; x.f = f;
  uint32_t r = x.i + 0x7FFF + ((x.i >> 16) & 1);
  return (unsigned short)(r >> 16);
}

// ---------------- per-row 128-pt DFT ----------------
__global__ void dft_kernel(const float* __restrict__ img, float2* __restrict__ col,
                           float2* __restrict__ tw) {
  __shared__ float row[128];
  __shared__ float2 twl[128];
  const int bh = blockIdx.x;      // b*128 + h
  const int i = threadIdx.x;      // 0..127
  row[i] = img[bh * 128 + i];
  float s, c;
  sincosf(PI2F * (float)i / 128.0f, &s, &c);
  twl[i] = make_float2(c, s);
  __syncthreads();
  if (bh == 0) tw[i] = twl[i];
  float sr = 0.f, si = 0.f;
  for (int w = 0; w < 128; ++w) {
    float v = row[w];
    float2 t = twl[(i * w) & 127];
    sr += v * t.x;
    si -= v * t.y;
  }
  col[bh * 128 + i] = make_float2(sr * (1.0f / 128.0f), si * (1.0f / 128.0f));
}

// ---------------- spectral sep + mask -> x0 channels-last [8][128][128][144] bf16
__global__ __launch_bounds__(256)
void sep_cl2_kernel(const float2* __restrict__ col, const float2* __restrict__ tw,
                    const float* __restrict__ maskE, unsigned short* __restrict__ x0) {
  __shared__ float2 cl[128];
  __shared__ float2 twl[128];
  const int bh = blockIdx.x;
  const int b = bh >> 7, h = bh & 127;
  const int tid = threadIdx.x;
  if (tid < 128) {
    cl[tid] = col[(b * 128 + h) * 128 + tid];
    twl[tid] = tw[tid];
  }
  __syncthreads();
  const int p = tid >> 1;          // pixel w
  const int c0 = (tid & 1) * 64;   // channel half
  unsigned short* dst = x0 + ((size_t)bh * 128 + p) * 144;
#pragma unroll
  for (int j = 0; j < 16; ++j) {
    ushort4 o;
#pragma unroll
    for (int q = 0; q < 4; ++q) {
      int c = c0 + 4 * j + q;
      float2 cv = cl[c];
      float2 t = twl[(p * c) & 127];
      float v = cv.x * t.x - cv.y * t.y;
      ((unsigned short*)&o)[q] = f2bf(v);
    }
    *reinterpret_cast<ushort4*>(dst + c0 + 4 * j) = o;
  }
  // mask channels 128-133 + zeros 134-143
  if (tid < 128) {
    const int w = tid;
    float v[6];
#pragma unroll
    for (int cm = 0; cm < 6; ++cm)
      v[cm] = maskE[(((size_t)(b * 6 + cm) * 128) + h) * 128 + w];
    unsigned short* d2 = x0 + ((size_t)bh * 128 + w) * 144 + 128;
    ushort4 m0, m1, mz;
    m0.x = f2bf(v[0]); m0.y = f2bf(v[1]); m0.z = f2bf(v[2]); m0.w = f2bf(v[3]);
    m1.x = f2bf(v[4]); m1.y = f2bf(v[5]); m1.z = 0; m1.w = 0;
    mz.x = 0; mz.y = 0; mz.z = 0; mz.w = 0;
    reinterpret_cast<ushort4*>(d2)[0] = m0;
    reinterpret_cast<ushort4*>(d2)[1] = m1;
    reinterpret_cast<ushort4*>(d2)[2] = mz;
    reinterpret_cast<ushort4*>(d2)[3] = mz;
  }
}

// ---------------- weight convert + permute: src[m][ci][t] fp32 -> dst[m][t*CINP+ci] bf16
template<int CIN, int CINP>
__global__ __launch_bounds__(256)
void cvtperm_kernel(const float* __restrict__ src, unsigned short* __restrict__ dst) {
  __shared__ unsigned short tile[16][68];
  const int m = blockIdx.y;
  const int ci0 = blockIdx.x * 64;
  const int tid = threadIdx.x;
  {
    const int ci = ci0 + (tid >> 2);
    const int t0 = (tid & 3) * 4;
    float4 v = make_float4(0.f, 0.f, 0.f, 0.f);
    if (ci < CIN) v = *reinterpret_cast<const float4*>(&src[((size_t)m * CIN + ci) * 16 + t0]);
    const int cr = tid >> 2;
    tile[t0 + 0][cr] = f2bf(v.x);
    tile[t0 + 1][cr] = f2bf(v.y);
    tile[t0 + 2][cr] = f2bf(v.z);
    tile[t0 + 3][cr] = f2bf(v.w);
  }
  __syncthreads();
  {
    const int t = tid >> 4;
    const int co = (tid & 15) * 4;
    const int ci = ci0 + co;
    if (ci < CINP) {
      ushort4 o;
      o.x = tile[t][co]; o.y = tile[t][co + 1]; o.z = tile[t][co + 2]; o.w = tile[t][co + 3];
      *reinterpret_cast<ushort4*>(&dst[(size_t)m * (16 * CINP) + (size_t)t * CINP + ci]) = o;
    }
  }
}

// ---------------- channels-last conv, 128x128 tile, BK=64 (2 chunks per barrier) -----
// k = tap*CINP + ci. Split-K over CHUNK ranges. 256 thr = 4 waves (2x2), wave 64x64.
// Per phase: stage 2 chunks (8 uint4/thread), ONE barrier, 32 MFMA/wave (2 halves).
// Each half keeps its own 64B-stride LDS array -> bank pattern identical to BK=32.
template<int CINP, int CSTOR, int COUT, int HI, int WI, int HO, int WO, int NSPLIT, bool FUSED>
__global__ __launch_bounds__(256, 2)
void conv_cl10_kernel(const unsigned short* __restrict__ X,
                      const unsigned short* __restrict__ Wt,
                      const float* __restrict__ bias,
                      unsigned short* __restrict__ Y,
                      unsigned short* __restrict__ P) {
  constexpr int KTOT = 16 * CINP;
  constexpr int CPT = CINP / 32;          // k-chunks per tap
  constexpr int NCHT = 16 * CPT;          // total chunks
  constexpr int CPS = NCHT / NSPLIT;      // chunks per split (even)
  constexpr int NPH = CPS / 2;            // phases: 40/32/32/16 — all even
  constexpr int HOWO = HO * WO;
  constexpr int LHW = __builtin_ctz(HOWO);
  constexpr int LWO = __builtin_ctz(WO);
  constexpr size_t PSTRIDE = (size_t)8 * HOWO * COUT;

  __shared__ __align__(16) unsigned short As[2][2][4096];  // [buf][half][row*32+slot]
  __shared__ __align__(16) unsigned short Bs[2][2][4096];

  const int tid = threadIdx.x;
  const int lane = tid & 63;
  const int wv = tid >> 6;
  const int wm = wv >> 1, wn = wv & 1;
  const int n0 = blockIdx.x * 128;
  const int m0 = blockIdx.y * 128;
  const int split = blockIdx.z;
  const int r = lane & 15, g = lane >> 4;

  const int row0 = tid >> 2;
  const int row1 = row0 + 64;
  const int chk = tid & 3;
  const int lw0 = row0 * 32 + (((chk + ((row0 >> 1) & 3)) & 3) * 8);
  const int lw1 = row1 * 32 + (((chk + ((row1 >> 1) & 3)) & 3) * 8);

  int bb0, bho0, bwo0, bb1, bho1, bwo1;
  {
    int rn0 = n0 + row0, rn1 = n0 + row1;
    bb0 = rn0 >> LHW; bb1 = rn1 >> LHW;
    int re0 = rn0 & (HOWO - 1), re1 = rn1 & (HOWO - 1);
    bho0 = re0 >> LWO; bho1 = re1 >> LWO;
    bwo0 = re0 & (WO - 1); bwo1 = re1 & (WO - 1);
  }

  const int start = split * CPS;
  int tapI = start / CPT, ccI = start % CPT;
  size_t boff0, boff1; bool bok0, bok1;
  auto tap_geom = [&](int t) {
    int kh = t >> 2, kw = t & 3;
    {
      int h = 2 * bho0 - 1 + kh, w = 2 * bwo0 - 1 + kw;
      bool hv = (unsigned)h < (unsigned)HI, wvv = (unsigned)w < (unsigned)WI;
      bok0 = hv && wvv;
      boff0 = (((size_t)bb0 * HI + (hv ? h : 0)) * WI + (wvv ? w : 0)) * (size_t)CSTOR;
    }
    {
      int h = 2 * bho1 - 1 + kh, w = 2 * bwo1 - 1 + kw;
      bool hv = (unsigned)h < (unsigned)HI, wvv = (unsigned)w < (unsigned)WI;
      bok1 = hv && wvv;
      boff1 = (((size_t)bb1 * HI + (hv ? h : 0)) * WI + (wvv ? w : 0)) * (size_t)CSTOR;
    }
  };
  tap_geom(tapI);

  // loads one chunk (current tapI,ccI) into 4 regs, then advances
  auto issue_half = [&](uint4& a0r, uint4& a1r, uint4& b0r, uint4& b1r) {
    const int kbase = tapI * CINP + ccI * 32 + chk * 8;
    a0r = *reinterpret_cast<const uint4*>(Wt + (size_t)(m0 + row0) * KTOT + kbase);
    a1r = *reinterpret_cast<const uint4*>(Wt + (size_t)(m0 + row1) * KTOT + kbase);
    int ci = ccI * 32 + chk * 8;
    bool ok0 = bok0, ok1 = bok1;
    int cic = ci;
    if constexpr (CSTOR < CINP) {
      if (ci >= CSTOR) { ok0 = false; ok1 = false; cic = 0; }
    }
    uint4 z = make_uint4(0u, 0u, 0u, 0u);
    uint4 v0 = *reinterpret_cast<const uint4*>(X + boff0 + cic);
    uint4 v1 = *reinterpret_cast<const uint4*>(X + boff1 + cic);
    b0r = ok0 ? v0 : z;
    b1r = ok1 ? v1 : z;
    ccI++;
    if (ccI == CPT) { ccI = 0; tapI++; if (tapI < 16) tap_geom(tapI); }
  };

  // two pipeline reg sets, 8 uint4 each (2 halves x {A row0, A row1, B row0, B row1})
  uint4 pA_a00, pA_a10, pA_b00, pA_b10, pA_a01, pA_a11, pA_b01, pA_b11;
  uint4 pB_a00, pB_a10, pB_b00, pB_b10, pB_a01, pB_a11, pB_b01, pB_b11;
  issue_half(pA_a00, pA_a10, pA_b00, pA_b10);
  issue_half(pA_a01, pA_a11, pA_b01, pA_b11);
  issue_half(pB_a00, pB_a10, pB_b00, pB_b10);
  issue_half(pB_a01, pB_a11, pB_b01, pB_b11);

  f32x4 acc[4][4] = {};

#define CONV_PHASE2(BUF, A00, A10, B00, B10, A01, A11, B01, B11, HASNEXT)               \
  *reinterpret_cast<uint4*>(&As[BUF][0][lw0]) = A00;                                    \
  *reinterpret_cast<uint4*>(&As[BUF][0][lw1]) = A10;                                    \
  *reinterpret_cast<uint4*>(&Bs[BUF][0][lw0]) = B00;                                    \
  *reinterpret_cast<uint4*>(&Bs[BUF][0][lw1]) = B10;                                    \
  *reinterpret_cast<uint4*>(&As[BUF][1][lw0]) = A01;                                    \
  *reinterpret_cast<uint4*>(&As[BUF][1][lw1]) = A11;                                    \
  *reinterpret_cast<uint4*>(&Bs[BUF][1][lw0]) = B01;                                    \
  *reinterpret_cast<uint4*>(&Bs[BUF][1][lw1]) = B11;                                    \
  __syncthreads();                                                                      \
  if (HASNEXT) {                                                                        \
    issue_half(A00, A10, B00, B10);                                                     \
    issue_half(A01, A11, B01, B11);                                                     \
  }                                                                                     \
  _Pragma("unroll")                                                                     \
  for (int hh = 0; hh < 2; ++hh) {                                                      \
    bf16x8 af[4], bf[4];                                                                \
    _Pragma("unroll")                                                                   \
    for (int mi = 0; mi < 4; ++mi) {                                                    \
      int rw = wm * 64 + mi * 16 + r;                                                   \
      af[mi] = *reinterpret_cast<const bf16x8*>(                                        \
          &As[BUF][hh][rw * 32 + (((g + ((rw >> 1) & 3)) & 3) * 8)]);                   \
    }                                                                                   \
    _Pragma("unroll")                                                                   \
    for (int ni = 0; ni < 4; ++ni) {                                                    \
      int rw = wn * 64 + ni * 16 + r;                                                   \
      bf[ni] = *reinterpret_cast<const bf16x8*>(                                        \
          &Bs[BUF][hh][rw * 32 + (((g + ((rw >> 1) & 3)) & 3) * 8)]);                   \
    }                                                                                   \
    _Pragma("unroll")                                                                   \
    for (int mi = 0; mi < 4; ++mi)                                                      \
      _Pragma("unroll")                                                                 \
      for (int ni = 0; ni < 4; ++ni)                                                    \
        acc[mi][ni] = __builtin_amdgcn_mfma_f32_16x16x32_bf16(af[mi], bf[ni],           \
                                                              acc[mi][ni], 0, 0, 0);    \
  }

  for (int ii = 0; ii < NPH / 2; ++ii) {
    CONV_PHASE2(0, pA_a00, pA_a10, pA_b00, pA_b10, pA_a01, pA_a11, pA_b01, pA_b11,
                (2 * ii + 2 < NPH))
    CONV_PHASE2(1, pB_a00, pB_a10, pB_b00, pB_b10, pB_a01, pB_a11, pB_b01, pB_b11,
                (2 * ii + 3 < NPH))
  }
#undef CONV_PHASE2

  // epilogue: C frag mapping col(n)=lane&15=r, row(m)=g*4+q
#pragma unroll
  for (int ni = 0; ni < 4; ++ni) {
    int n = n0 + wn * 64 + ni * 16 + r;
    int b = n >> LHW;
    int rem = n & (HOWO - 1);
    size_t obase = ((size_t)b * HOWO + rem) * COUT;
#pragma unroll
    for (int mi = 0; mi < 4; ++mi) {
      int mb = m0 + wm * 64 + mi * 16 + g * 4;
      f32x4 a = acc[mi][ni];
      if constexpr (FUSED) {
        float v0 = a[0] + bias[mb + 0]; v0 = v0 > 0.f ? v0 : 0.2f * v0;
        float v1 = a[1] + bias[mb + 1]; v1 = v1 > 0.f ? v1 : 0.2f * v1;
        float v2 = a[2] + bias[mb + 2]; v2 = v2 > 0.f ? v2 : 0.2f * v2;
        float v3 = a[3] + bias[mb + 3]; v3 = v3 > 0.f ? v3 : 0.2f * v3;
        ushort4 o;
        o.x = f2bf(v0); o.y = f2bf(v1); o.z = f2bf(v2); o.w = f2bf(v3);
        *reinterpret_cast<ushort4*>(&Y[obase + mb]) = o;
      } else {
        ushort4 o;
        o.x = f2bf(a[0]); o.y = f2bf(a[1]); o.z = f2bf(a[2]); o.w = f2bf(a[3]);
        *reinterpret_cast<ushort4*>(&P[split * PSTRIDE + obase + mb]) = o;
      }
    }
  }
}

// ---------------- NHWC split-reduce (bf16 partials) + instance norm + lrelu -> bf16 --
template<int HOWO, int COUT, int NSPLIT>
__global__ __launch_bounds__(256)
void inorm_bf_kernel(const unsigned short* __restrict__ P, unsigned short* __restrict__ Y) {
  constexpr int PER = HOWO / 32;
  constexpr size_t PSTRIDE = (size_t)8 * HOWO * COUT;
  const int b = blockIdx.y;
  const int cl = threadIdx.x & 7;
  const int c = blockIdx.x * 8 + cl;
  const int hw0 = threadIdx.x >> 3;   // 0..31
  const unsigned short* base = P + ((size_t)b * HOWO) * COUT + c;
  float v[PER];
  float s1 = 0.f, s2 = 0.f;
#pragma unroll
  for (int j = 0; j < PER; ++j) {
    int hw = hw0 + j * 32;
    float x = 0.f;
#pragma unroll
    for (int s = 0; s < NSPLIT; ++s) x += bf2f(base[s * PSTRIDE + (size_t)hw * COUT]);
    v[j] = x; s1 += x; s2 += x * x;
  }
  __shared__ float r1[32][9], r2[32][9];
  __shared__ float ms[8], rs[8];
  r1[hw0][cl] = s1; r2[hw0][cl] = s2;
  __syncthreads();
  if (threadIdx.x < 8) {
    float a1 = 0.f, a2 = 0.f;
#pragma unroll
    for (int i = 0; i < 32; ++i) { a1 += r1[i][threadIdx.x]; a2 += r2[i][threadIdx.x]; }
    float mean = a1 * (1.0f / HOWO);
    float var = a2 * (1.0f / HOWO) - mean * mean;
    ms[threadIdx.x] = mean;
    rs[threadIdx.x] = rsqrtf(var + 1e-5f);
  }
  __syncthreads();
  const float mean = ms[cl], rstd = rs[cl];
  unsigned short* yb = Y + ((size_t)b * HOWO) * COUT + c;
#pragma unroll
  for (int j = 0; j < PER; ++j) {
    int hw = hw0 + j * 32;
    float t = (v[j] - mean) * rstd;
    t = t > 0.f ? t : 0.2f * t;
    yb[(size_t)hw * COUT] = f2bf(t);
  }
}

// ---------------- NHWC avg pool 8x8: [8][64][1024] -> pooled [8][1024] fp32 --------
__global__ __launch_bounds__(256)
void pool_cl_kernel(const unsigned short* __restrict__ X, float* __restrict__ pooled) {
  const int b = blockIdx.x;
  const int c4 = threadIdx.x * 4;
  float4 acc = make_float4(0.f, 0.f, 0.f, 0.f);
  for (int hw = 0; hw < 64; ++hw) {
    ushort4 v = *reinterpret_cast<const ushort4*>(&X[((size_t)b * 64 + hw) * 1024 + c4]);
    acc.x += bf2f(v.x); acc.y += bf2f(v.y); acc.z += bf2f(v.z); acc.w += bf2f(v.w);
  }
  acc.x *= (1.0f / 64.0f); acc.y *= (1.0f / 64.0f);
  acc.z *= (1.0f / 64.0f); acc.w *= (1.0f / 64.0f);
  *reinterpret_cast<float4*>(&pooled[b * 1024 + c4]) = acc;
}

// ---------------- final linear ----------------
__global__ __launch_bounds__(64)
void fc_kernel(const float* __restrict__ pooled, const float* __restrict__ w4,
               const float* __restrict__ b4, float* __restrict__ out) {
  const int bo = blockIdx.x;
  const int b = bo >> 7, o = bo & 127;
  const int lane = threadIdx.x;
  float s = 0.f;
#pragma unroll
  for (int j = 0; j < 16; ++j) {
    int c = lane + j * 64;
    s += pooled[b * 1024 + c] * w4[o * 1024 + c];
  }
#pragma unroll
  for (int off = 32; off > 0; off >>= 1) s += __shfl_xor(s, off);
  if (lane == 0) out[bo] = s + b4[o];
}

extern "C" void kernel_launch(void* const* d_in, const int* in_sizes, int n_in,
                              void* d_out, int out_size, void* d_ws, size_t ws_size,
                              hipStream_t stream) {
  (void)in_sizes; (void)n_in; (void)out_size; (void)ws_size;
  const float* image = (const float*)d_in[0];
  const float* maskE = (const float*)d_in[1];
  const float* w0 = (const float*)d_in[2];
  const float* b0 = (const float*)d_in[3];
  const float* w1 = (const float*)d_in[4];
  const float* w2 = (const float*)d_in[6];
  const float* w3 = (const float*)d_in[8];
  const float* w4 = (const float*)d_in[10];
  const float* b4 = (const float*)d_in[11];
  float* out = (float*)d_out;

  char* ws = (char*)d_ws;
  size_t off = 0;
  auto alloc = [&](size_t bytes) -> void* {
    void* p = ws + off;
    off = (off + bytes + 255) & ~(size_t)255;
    return p;
  };

  const size_t X0BYTES = (size_t)8 * 128 * 128 * 144 * 2;   // 37,748,736
  unsigned short* wbuf = (unsigned short*)alloc((size_t)1024 * 16384 * 2);
  char* bufA = (char*)alloc(X0BYTES + 256);
  char* bufB = (char*)alloc((size_t)8 * 4096 * 256 * 2);
  float2* col = (float2*)alloc((size_t)131072 * sizeof(float2));
  float2* tw = (float2*)alloc(128 * sizeof(float2));
  float* pooled = (float*)alloc(8192 * 4);

  unsigned short* x0 = (unsigned short*)bufA;
  unsigned short* part = (unsigned short*)bufA;
  unsigned short* a0 = (unsigned short*)bufB;
  unsigned short* a1 = (unsigned short*)bufB;
  unsigned short* a2 = (unsigned short*)bufB;
  unsigned short* a3 = (unsigned short*)bufB;

  // spectral map (channels-last)
  dft_kernel<<<1024, 128, 0, stream>>>(image, col, tw);
  sep_cl2_kernel<<<1024, 256, 0, stream>>>(col, tw, maskE, x0);

  // conv0: 134(pad160)->256, fused bias+lrelu, full K. 512 blocks (2/CU).
  cvtperm_kernel<134, 160><<<dim3(3, 256), 256, 0, stream>>>(w0, wbuf);
  conv_cl10_kernel<160, 144, 256, 128, 128, 64, 64, 1, true>
      <<<dim3(256, 2, 1), 256, 0, stream>>>(x0, wbuf, b0, a0, nullptr);

  // conv1: 256->512, split 2. 512 blocks.
  cvtperm_kernel<256, 256><<<dim3(4, 512), 256, 0, stream>>>(w1, wbuf);
  conv_cl10_kernel<256, 256, 512, 64, 64, 32, 32, 2, false>
      <<<dim3(64, 4, 2), 256, 0, stream>>>(a0, wbuf, nullptr, nullptr, part);
  inorm_bf_kernel<1024, 512, 2><<<dim3(64, 8), 256, 0, stream>>>(part, a1);

  // conv2: 512->1024, split 4. 512 blocks.
  cvtperm_kernel<512, 512><<<dim3(8, 1024), 256, 0, stream>>>(w2, wbuf);
  conv_cl10_kernel<512, 512, 1024, 32, 32, 16, 16, 4, false>
      <<<dim3(16, 8, 4), 256, 0, stream>>>(a1, wbuf, nullptr, nullptr, part);
  inorm_bf_kernel<256, 1024, 4><<<dim3(128, 8), 256, 0, stream>>>(part, a2);

  // conv3: 1024->1024, split 16. 512 blocks.
  cvtperm_kernel<1024, 1024><<<dim3(16, 1024), 256, 0, stream>>>(w3, wbuf);
  conv_cl10_kernel<1024, 1024, 1024, 16, 16, 8, 8, 16, false>
      <<<dim3(4, 8, 16), 256, 0, stream>>>(a2, wbuf, nullptr, nullptr, part);
  inorm_bf_kernel<64, 1024, 16><<<dim3(128, 8), 256, 0, stream>>>(part, a3);

  // pool + fc
  pool_cl_kernel<<<8, 256, 0, stream>>>(a3, pooled);
  fc_kernel<<<1024, 64, 0, stream>>>(pooled, w4, b4, out);
}

// Round 20
// 312.625 us; speedup vs baseline: 1.0274x; 1.0274x over previous
//
#include <hip/hip_runtime.h>
#include <hip/hip_bf16.h>
#include <cstdint>
#include <cstddef>

typedef __attribute__((ext_vector_type(8))) short bf16x8;
typedef __attribute__((ext_vector_type(4))) float f32x4;

#define PI2F 6.283185307179586f

__device__ __forceinline__ float bf2f(unsigned short u) {
  union { float f; uint32_t i; } x; x.i = ((uint32_t)u) << 16; return x.f;
}
__device__ __forceinline__ unsigned short f2bf(float f) {
  union { float f; uint32_t i; } x; x.f = f;
  uint32_t r = x.i + 0x7FFF + ((x.i >> 16) & 1);
  return (unsigned short)(r >> 16);
}

// ---------------- per-row 128-pt DFT ----------------
__global__ void dft_kernel(const float* __restrict__ img, float2* __restrict__ col,
                           float2* __restrict__ tw) {
  __shared__ float row[128];
  __shared__ float2 twl[128];
  const int bh = blockIdx.x;      // b*128 + h
  const int i = threadIdx.x;      // 0..127
  row[i] = img[bh * 128 + i];
  float s, c;
  sincosf(PI2F * (float)i / 128.0f, &s, &c);
  twl[i] = make_float2(c, s);
  __syncthreads();
  if (bh == 0) tw[i] = twl[i];
  float sr = 0.f, si = 0.f;
  for (int w = 0; w < 128; ++w) {
    float v = row[w];
    float2 t = twl[(i * w) & 127];
    sr += v * t.x;
    si -= v * t.y;
  }
  col[bh * 128 + i] = make_float2(sr * (1.0f / 128.0f), si * (1.0f / 128.0f));
}

// ---------------- spectral sep + mask -> x0 channels-last [8][128][128][144] bf16
__global__ __launch_bounds__(256)
void sep_cl2_kernel(const float2* __restrict__ col, const float2* __restrict__ tw,
                    const float* __restrict__ maskE, unsigned short* __restrict__ x0) {
  __shared__ float2 cl[128];
  __shared__ float2 twl[128];
  const int bh = blockIdx.x;
  const int b = bh >> 7, h = bh & 127;
  const int tid = threadIdx.x;
  if (tid < 128) {
    cl[tid] = col[(b * 128 + h) * 128 + tid];
    twl[tid] = tw[tid];
  }
  __syncthreads();
  const int p = tid >> 1;          // pixel w
  const int c0 = (tid & 1) * 64;   // channel half
  unsigned short* dst = x0 + ((size_t)bh * 128 + p) * 144;
#pragma unroll
  for (int j = 0; j < 16; ++j) {
    ushort4 o;
#pragma unroll
    for (int q = 0; q < 4; ++q) {
      int c = c0 + 4 * j + q;
      float2 cv = cl[c];
      float2 t = twl[(p * c) & 127];
      float v = cv.x * t.x - cv.y * t.y;
      ((unsigned short*)&o)[q] = f2bf(v);
    }
    *reinterpret_cast<ushort4*>(dst + c0 + 4 * j) = o;
  }
  // mask channels 128-133 + zeros 134-143
  if (tid < 128) {
    const int w = tid;
    float v[6];
#pragma unroll
    for (int cm = 0; cm < 6; ++cm)
      v[cm] = maskE[(((size_t)(b * 6 + cm) * 128) + h) * 128 + w];
    unsigned short* d2 = x0 + ((size_t)bh * 128 + w) * 144 + 128;
    ushort4 m0, m1, mz;
    m0.x = f2bf(v[0]); m0.y = f2bf(v[1]); m0.z = f2bf(v[2]); m0.w = f2bf(v[3]);
    m1.x = f2bf(v[4]); m1.y = f2bf(v[5]); m1.z = 0; m1.w = 0;
    mz.x = 0; mz.y = 0; mz.z = 0; mz.w = 0;
    reinterpret_cast<ushort4*>(d2)[0] = m0;
    reinterpret_cast<ushort4*>(d2)[1] = m1;
    reinterpret_cast<ushort4*>(d2)[2] = mz;
    reinterpret_cast<ushort4*>(d2)[3] = mz;
  }
}

// ---------------- weight convert + permute: src[m][ci][t] fp32 -> dst[m][t*CINP+ci] bf16
template<int CIN, int CINP>
__global__ __launch_bounds__(256)
void cvtperm_kernel(const float* __restrict__ src, unsigned short* __restrict__ dst) {
  __shared__ unsigned short tile[16][68];
  const int m = blockIdx.y;
  const int ci0 = blockIdx.x * 64;
  const int tid = threadIdx.x;
  {
    const int ci = ci0 + (tid >> 2);
    const int t0 = (tid & 3) * 4;
    float4 v = make_float4(0.f, 0.f, 0.f, 0.f);
    if (ci < CIN) v = *reinterpret_cast<const float4*>(&src[((size_t)m * CIN + ci) * 16 + t0]);
    const int cr = tid >> 2;
    tile[t0 + 0][cr] = f2bf(v.x);
    tile[t0 + 1][cr] = f2bf(v.y);
    tile[t0 + 2][cr] = f2bf(v.z);
    tile[t0 + 3][cr] = f2bf(v.w);
  }
  __syncthreads();
  {
    const int t = tid >> 4;
    const int co = (tid & 15) * 4;
    const int ci = ci0 + co;
    if (ci < CINP) {
      ushort4 o;
      o.x = tile[t][co]; o.y = tile[t][co + 1]; o.z = tile[t][co + 2]; o.w = tile[t][co + 3];
      *reinterpret_cast<ushort4*>(&dst[(size_t)m * (16 * CINP) + (size_t)t * CINP + ci]) = o;
    }
  }
}

// ---------------- channels-last conv, 128x128 tile, LDS dbuf + depth-2 reg prefetch --
// k = tap*CINP + ci. Split-K over CHUNK ranges (CPS = 16*CPT/NSPLIT chunks per split).
// 256 thr = 4 waves (2x2), wave tile 64x64 (4x4 frags). One barrier per 32-k-step.
// r18 champion + T1 XCD-aware bijective chunked swizzle on the n-dimension.
template<int CINP, int CSTOR, int COUT, int HI, int WI, int HO, int WO, int NSPLIT, bool FUSED>
__global__ __launch_bounds__(256, 2)
void conv_cl11_kernel(const unsigned short* __restrict__ X,
                      const unsigned short* __restrict__ Wt,
                      const float* __restrict__ bias,
                      unsigned short* __restrict__ Y,
                      unsigned short* __restrict__ P) {
  constexpr int KTOT = 16 * CINP;
  constexpr int CPT = CINP / 32;          // k-chunks per tap
  constexpr int NCHT = 16 * CPT;          // total chunks
  constexpr int CPS = NCHT / NSPLIT;      // chunks per split
  constexpr int HOWO = HO * WO;
  constexpr int LHW = __builtin_ctz(HOWO);
  constexpr int LWO = __builtin_ctz(WO);
  constexpr size_t PSTRIDE = (size_t)8 * HOWO * COUT;
  constexpr int NIT = CPS;                // 80/64/64/32 — all even

  __shared__ __align__(16) unsigned short As[2][128 * 32];
  __shared__ __align__(16) unsigned short Bs[2][128 * 32];

  const int tid = threadIdx.x;
  const int lane = tid & 63;
  const int wv = tid >> 6;
  const int wm = wv >> 1, wn = wv & 1;
  // T1: XCD-aware chunked swizzle (bijective when gridDim.x % 8 == 0; wgid%8 == bx%8
  // since gridDim.x ≡ 0 mod 8, so each XCD gets a contiguous n-chunk).
  int bxr = blockIdx.x;
  {
    int gx = gridDim.x;
    if ((gx & 7) == 0) bxr = (bxr & 7) * (gx >> 3) + (bxr >> 3);
  }
  const int n0 = bxr * 128;
  const int m0 = blockIdx.y * 128;
  const int split = blockIdx.z;
  const int r = lane & 15, g = lane >> 4;

  // staging: thread handles rows row0, row0+64, 16B chunk chk (swizzled slot)
  const int row0 = tid >> 2;
  const int row1 = row0 + 64;
  const int chk = tid & 3;
  const int lw0 = row0 * 32 + (((chk + ((row0 >> 1) & 3)) & 3) * 8);
  const int lw1 = row1 * 32 + (((chk + ((row1 >> 1) & 3)) & 3) * 8);

  int bb0, bho0, bwo0, bb1, bho1, bwo1;
  {
    int rn0 = n0 + row0, rn1 = n0 + row1;
    bb0 = rn0 >> LHW; bb1 = rn1 >> LHW;
    int re0 = rn0 & (HOWO - 1), re1 = rn1 & (HOWO - 1);
    bho0 = re0 >> LWO; bho1 = re1 >> LWO;
    bwo0 = re0 & (WO - 1); bwo1 = re1 & (WO - 1);
  }

  const int start = split * CPS;
  int tapI = start / CPT, ccI = start % CPT;   // issue pointer (chunk-range split)
  size_t boff0, boff1; bool bok0, bok1;
  auto tap_geom = [&](int t) {
    int kh = t >> 2, kw = t & 3;
    {
      int h = 2 * bho0 - 1 + kh, w = 2 * bwo0 - 1 + kw;
      bool hv = (unsigned)h < (unsigned)HI, wvv = (unsigned)w < (unsigned)WI;
      bok0 = hv && wvv;
      boff0 = (((size_t)bb0 * HI + (hv ? h : 0)) * WI + (wvv ? w : 0)) * (size_t)CSTOR;
    }
    {
      int h = 2 * bho1 - 1 + kh, w = 2 * bwo1 - 1 + kw;
      bool hv = (unsigned)h < (unsigned)HI, wvv = (unsigned)w < (unsigned)WI;
      bok1 = hv && wvv;
      boff1 = (((size_t)bb1 * HI + (hv ? h : 0)) * WI + (wvv ? w : 0)) * (size_t)CSTOR;
    }
  };
  tap_geom(tapI);

  auto issue = [&](uint4& a0r, uint4& a1r, uint4& b0r, uint4& b1r) {
    const int kbase = tapI * CINP + ccI * 32 + chk * 8;
    a0r = *reinterpret_cast<const uint4*>(Wt + (size_t)(m0 + row0) * KTOT + kbase);
    a1r = *reinterpret_cast<const uint4*>(Wt + (size_t)(m0 + row1) * KTOT + kbase);
    int ci = ccI * 32 + chk * 8;
    bool ok0 = bok0, ok1 = bok1;
    int cic = ci;
    if constexpr (CSTOR < CINP) {
      if (ci >= CSTOR) { ok0 = false; ok1 = false; cic = 0; }
    }
    uint4 z = make_uint4(0u, 0u, 0u, 0u);
    uint4 v0 = *reinterpret_cast<const uint4*>(X + boff0 + cic);
    uint4 v1 = *reinterpret_cast<const uint4*>(X + boff1 + cic);
    b0r = ok0 ? v0 : z;
    b1r = ok1 ? v1 : z;
  };
  auto advance = [&]() {
    ccI++;
    if (ccI == CPT) { ccI = 0; tapI++; if (tapI < 16) tap_geom(tapI); }
  };

  uint4 avA0, avA1, bvA0, bvA1;
  uint4 avB0, avB1, bvB0, bvB1;
  issue(avA0, avA1, bvA0, bvA1); advance();
  issue(avB0, avB1, bvB0, bvB1); advance();

  f32x4 acc[4][4] = {};

#define CONV_PHASE(BUF, AV0, AV1, BV0, BV1, HASNEXT)                                    \
  *reinterpret_cast<uint4*>(&As[BUF][lw0]) = AV0;                                       \
  *reinterpret_cast<uint4*>(&As[BUF][lw1]) = AV1;                                       \
  *reinterpret_cast<uint4*>(&Bs[BUF][lw0]) = BV0;                                       \
  *reinterpret_cast<uint4*>(&Bs[BUF][lw1]) = BV1;                                       \
  __syncthreads();                                                                      \
  if (HASNEXT) { issue(AV0, AV1, BV0, BV1); advance(); }                                \
  {                                                                                     \
    bf16x8 af[4], bf[4];                                                                \
    _Pragma("unroll")                                                                   \
    for (int mi = 0; mi < 4; ++mi) {                                                    \
      int rw = wm * 64 + mi * 16 + r;                                                   \
      af[mi] = *reinterpret_cast<const bf16x8*>(                                        \
          &As[BUF][rw * 32 + (((g + ((rw >> 1) & 3)) & 3) * 8)]);                       \
    }                                                                                   \
    _Pragma("unroll")                                                                   \
    for (int ni = 0; ni < 4; ++ni) {                                                    \
      int rw = wn * 64 + ni * 16 + r;                                                   \
      bf[ni] = *reinterpret_cast<const bf16x8*>(                                        \
          &Bs[BUF][rw * 32 + (((g + ((rw >> 1) & 3)) & 3) * 8)]);                       \
    }                                                                                   \
    _Pragma("unroll")                                                                   \
    for (int mi = 0; mi < 4; ++mi)                                                      \
      _Pragma("unroll")                                                                 \
      for (int ni = 0; ni < 4; ++ni)                                                    \
        acc[mi][ni] = __builtin_amdgcn_mfma_f32_16x16x32_bf16(af[mi], bf[ni],           \
                                                              acc[mi][ni], 0, 0, 0);    \
  }

  for (int ii = 0; ii < NIT / 2; ++ii) {
    CONV_PHASE(0, avA0, avA1, bvA0, bvA1, (2 * ii + 2 < NIT))
    CONV_PHASE(1, avB0, avB1, bvB0, bvB1, (2 * ii + 3 < NIT))
  }
#undef CONV_PHASE

  // epilogue: C frag mapping col(n)=lane&15=r, row(m)=g*4+q
#pragma unroll
  for (int ni = 0; ni < 4; ++ni) {
    int n = n0 + wn * 64 + ni * 16 + r;
    int b = n >> LHW;
    int rem = n & (HOWO - 1);
    size_t obase = ((size_t)b * HOWO + rem) * COUT;
#pragma unroll
    for (int mi = 0; mi < 4; ++mi) {
      int mb = m0 + wm * 64 + mi * 16 + g * 4;
      f32x4 a = acc[mi][ni];
      if constexpr (FUSED) {
        float v0 = a[0] + bias[mb + 0]; v0 = v0 > 0.f ? v0 : 0.2f * v0;
        float v1 = a[1] + bias[mb + 1]; v1 = v1 > 0.f ? v1 : 0.2f * v1;
        float v2 = a[2] + bias[mb + 2]; v2 = v2 > 0.f ? v2 : 0.2f * v2;
        float v3 = a[3] + bias[mb + 3]; v3 = v3 > 0.f ? v3 : 0.2f * v3;
        ushort4 o;
        o.x = f2bf(v0); o.y = f2bf(v1); o.z = f2bf(v2); o.w = f2bf(v3);
        *reinterpret_cast<ushort4*>(&Y[obase + mb]) = o;
      } else {
        ushort4 o;
        o.x = f2bf(a[0]); o.y = f2bf(a[1]); o.z = f2bf(a[2]); o.w = f2bf(a[3]);
        *reinterpret_cast<ushort4*>(&P[split * PSTRIDE + obase + mb]) = o;
      }
    }
  }
}

// ---------------- NHWC split-reduce (bf16 partials) + instance norm + lrelu -> bf16 --
template<int HOWO, int COUT, int NSPLIT>
__global__ __launch_bounds__(256)
void inorm_bf_kernel(const unsigned short* __restrict__ P, unsigned short* __restrict__ Y) {
  constexpr int PER = HOWO / 32;
  constexpr size_t PSTRIDE = (size_t)8 * HOWO * COUT;
  const int b = blockIdx.y;
  const int cl = threadIdx.x & 7;
  const int c = blockIdx.x * 8 + cl;
  const int hw0 = threadIdx.x >> 3;   // 0..31
  const unsigned short* base = P + ((size_t)b * HOWO) * COUT + c;
  float v[PER];
  float s1 = 0.f, s2 = 0.f;
#pragma unroll
  for (int j = 0; j < PER; ++j) {
    int hw = hw0 + j * 32;
    float x = 0.f;
#pragma unroll
    for (int s = 0; s < NSPLIT; ++s) x += bf2f(base[s * PSTRIDE + (size_t)hw * COUT]);
    v[j] = x; s1 += x; s2 += x * x;
  }
  __shared__ float r1[32][9], r2[32][9];
  __shared__ float ms[8], rs[8];
  r1[hw0][cl] = s1; r2[hw0][cl] = s2;
  __syncthreads();
  if (threadIdx.x < 8) {
    float a1 = 0.f, a2 = 0.f;
#pragma unroll
    for (int i = 0; i < 32; ++i) { a1 += r1[i][threadIdx.x]; a2 += r2[i][threadIdx.x]; }
    float mean = a1 * (1.0f / HOWO);
    float var = a2 * (1.0f / HOWO) - mean * mean;
    ms[threadIdx.x] = mean;
    rs[threadIdx.x] = rsqrtf(var + 1e-5f);
  }
  __syncthreads();
  const float mean = ms[cl], rstd = rs[cl];
  unsigned short* yb = Y + ((size_t)b * HOWO) * COUT + c;
#pragma unroll
  for (int j = 0; j < PER; ++j) {
    int hw = hw0 + j * 32;
    float t = (v[j] - mean) * rstd;
    t = t > 0.f ? t : 0.2f * t;
    yb[(size_t)hw * COUT] = f2bf(t);
  }
}

// ---------------- NHWC avg pool 8x8: [8][64][1024] -> pooled [8][1024] fp32 --------
__global__ __launch_bounds__(256)
void pool_cl_kernel(const unsigned short* __restrict__ X, float* __restrict__ pooled) {
  const int b = blockIdx.x;
  const int c4 = threadIdx.x * 4;
  float4 acc = make_float4(0.f, 0.f, 0.f, 0.f);
  for (int hw = 0; hw < 64; ++hw) {
    ushort4 v = *reinterpret_cast<const ushort4*>(&X[((size_t)b * 64 + hw) * 1024 + c4]);
    acc.x += bf2f(v.x); acc.y += bf2f(v.y); acc.z += bf2f(v.z); acc.w += bf2f(v.w);
  }
  acc.x *= (1.0f / 64.0f); acc.y *= (1.0f / 64.0f);
  acc.z *= (1.0f / 64.0f); acc.w *= (1.0f / 64.0f);
  *reinterpret_cast<float4*>(&pooled[b * 1024 + c4]) = acc;
}

// ---------------- final linear ----------------
__global__ __launch_bounds__(64)
void fc_kernel(const float* __restrict__ pooled, const float* __restrict__ w4,
               const float* __restrict__ b4, float* __restrict__ out) {
  const int bo = blockIdx.x;
  const int b = bo >> 7, o = bo & 127;
  const int lane = threadIdx.x;
  float s = 0.f;
#pragma unroll
  for (int j = 0; j < 16; ++j) {
    int c = lane + j * 64;
    s += pooled[b * 1024 + c] * w4[o * 1024 + c];
  }
#pragma unroll
  for (int off = 32; off > 0; off >>= 1) s += __shfl_xor(s, off);
  if (lane == 0) out[bo] = s + b4[o];
}

extern "C" void kernel_launch(void* const* d_in, const int* in_sizes, int n_in,
                              void* d_out, int out_size, void* d_ws, size_t ws_size,
                              hipStream_t stream) {
  (void)in_sizes; (void)n_in; (void)out_size; (void)ws_size;
  const float* image = (const float*)d_in[0];
  const float* maskE = (const float*)d_in[1];
  const float* w0 = (const float*)d_in[2];
  const float* b0 = (const float*)d_in[3];
  const float* w1 = (const float*)d_in[4];
  const float* w2 = (const float*)d_in[6];
  const float* w3 = (const float*)d_in[8];
  const float* w4 = (const float*)d_in[10];
  const float* b4 = (const float*)d_in[11];
  float* out = (float*)d_out;

  char* ws = (char*)d_ws;
  size_t off = 0;
  auto alloc = [&](size_t bytes) -> void* {
    void* p = ws + off;
    off = (off + bytes + 255) & ~(size_t)255;
    return p;
  };

  const size_t X0BYTES = (size_t)8 * 128 * 128 * 144 * 2;   // 37,748,736
  // wbuf: one 32MB permuted-weight buffer, stream-ordered reuse.
  unsigned short* wbuf = (unsigned short*)alloc((size_t)1024 * 16384 * 2);
  // bufA: x0cl (37.75MB), later bf16 split partials (<=16.8MB).
  char* bufA = (char*)alloc(X0BYTES + 256);
  // bufB: NHWC activations a0 (16.8MB) / a1 / a2 / a3, sequential reuse.
  char* bufB = (char*)alloc((size_t)8 * 4096 * 256 * 2);
  float2* col = (float2*)alloc((size_t)131072 * sizeof(float2));
  float2* tw = (float2*)alloc(128 * sizeof(float2));
  float* pooled = (float*)alloc(8192 * 4);

  unsigned short* x0 = (unsigned short*)bufA;
  unsigned short* part = (unsigned short*)bufA;
  unsigned short* a0 = (unsigned short*)bufB;
  unsigned short* a1 = (unsigned short*)bufB;
  unsigned short* a2 = (unsigned short*)bufB;
  unsigned short* a3 = (unsigned short*)bufB;

  // spectral map (channels-last)
  dft_kernel<<<1024, 128, 0, stream>>>(image, col, tw);
  sep_cl2_kernel<<<1024, 256, 0, stream>>>(col, tw, maskE, x0);

  // conv0: 134(pad160)->256, fused bias+lrelu, full K. 512 blocks (2/CU).
  cvtperm_kernel<134, 160><<<dim3(3, 256), 256, 0, stream>>>(w0, wbuf);
  conv_cl11_kernel<160, 144, 256, 128, 128, 64, 64, 1, true>
      <<<dim3(256, 2, 1), 256, 0, stream>>>(x0, wbuf, b0, a0, nullptr);

  // conv1: 256->512, split 2 (64 chunks each). 512 blocks.
  cvtperm_kernel<256, 256><<<dim3(4, 512), 256, 0, stream>>>(w1, wbuf);
  conv_cl11_kernel<256, 256, 512, 64, 64, 32, 32, 2, false>
      <<<dim3(64, 4, 2), 256, 0, stream>>>(a0, wbuf, nullptr, nullptr, part);
  inorm_bf_kernel<1024, 512, 2><<<dim3(64, 8), 256, 0, stream>>>(part, a1);

  // conv2: 512->1024, split 4 (64 chunks each). 512 blocks.
  cvtperm_kernel<512, 512><<<dim3(8, 1024), 256, 0, stream>>>(w2, wbuf);
  conv_cl11_kernel<512, 512, 1024, 32, 32, 16, 16, 4, false>
      <<<dim3(16, 8, 4), 256, 0, stream>>>(a1, wbuf, nullptr, nullptr, part);
  inorm_bf_kernel<256, 1024, 4><<<dim3(128, 8), 256, 0, stream>>>(part, a2);

  // conv3: 1024->1024, split 16 (32 chunks each). 512 blocks. (gx=4: no swizzle)
  cvtperm_kernel<1024, 1024><<<dim3(16, 1024), 256, 0, stream>>>(w3, wbuf);
  conv_cl11_kernel<1024, 1024, 1024, 16, 16, 8, 8, 16, false>
      <<<dim3(4, 8, 16), 256, 0, stream>>>(a2, wbuf, nullptr, nullptr, part);
  inorm_bf_kernel<64, 1024, 16><<<dim3(128, 8), 256, 0, stream>>>(part, a3);

  // pool + fc
  pool_cl_kernel<<<8, 256, 0, stream>>>(a3, pooled);
  fc_kernel<<<1024, 64, 0, stream>>>(pooled, w4, b4, out);
}

// Round 21
// 303.291 us; speedup vs baseline: 1.0591x; 1.0308x over previous
//
#include <hip/hip_runtime.h>
#include <hip/hip_bf16.h>
#include <cstdint>
#include <cstddef>

typedef __attribute__((ext_vector_type(8))) short bf16x8;
typedef __attribute__((ext_vector_type(4))) float f32x4;

#define PI2F 6.283185307179586f

__device__ __forceinline__ float bf2f(unsigned short u) {
  union { float f; uint32_t i; } x; x.i = ((uint32_t)u) << 16; return x.f;
}
__device__ __forceinline__ unsigned short f2bf(float f) {
  union { float f; uint32_t i; } x; x.f = f;
  uint32_t r = x.i + 0x7FFF + ((x.i >> 16) & 1);
  return (unsigned short)(r >> 16);
}

// ---------------- fused DFT + spectral sep + mask -> x0 [8][128][128][144] bf16 ------
// grid 1024 (b*128+h), block 256. DFT of the image row computed in-LDS (2 half-sums),
// then separation with vectorized ushort4 stores. Removes dft kernel + col round-trip.
__global__ __launch_bounds__(256)
void sep_cl3_kernel(const float* __restrict__ img, const float* __restrict__ maskE,
                    unsigned short* __restrict__ x0) {
  __shared__ float rowm[128];
  __shared__ float2 twl[128];
  __shared__ float2 halfs[2][128];
  __shared__ float2 cl[128];
  const int bh = blockIdx.x;
  const int b = bh >> 7, h = bh & 127;
  const int tid = threadIdx.x;
  if (tid < 128) {
    rowm[tid] = img[(size_t)bh * 128 + tid];
    float s, c;
    sincosf(PI2F * (float)tid / 128.0f, &s, &c);
    twl[tid] = make_float2(c, s);
  }
  __syncthreads();
  {
    const int c = tid & 127;
    const int hf = tid >> 7;          // 0/1: which 64-w half
    float sr = 0.f, si = 0.f;
#pragma unroll 8
    for (int j = 0; j < 64; ++j) {
      int w = hf * 64 + j;
      float v = rowm[w];
      float2 t = twl[(c * w) & 127];
      sr += v * t.x;
      si -= v * t.y;
    }
    halfs[hf][c] = make_float2(sr, si);
  }
  __syncthreads();
  if (tid < 128) {
    float2 a = halfs[0][tid], bsum = halfs[1][tid];
    cl[tid] = make_float2((a.x + bsum.x) * (1.0f / 128.0f),
                          (a.y + bsum.y) * (1.0f / 128.0f));
  }
  __syncthreads();
  const int p = tid >> 1;          // pixel w
  const int c0 = (tid & 1) * 64;   // channel half
  unsigned short* dst = x0 + ((size_t)bh * 128 + p) * 144;
#pragma unroll
  for (int j = 0; j < 16; ++j) {
    ushort4 o;
#pragma unroll
    for (int q = 0; q < 4; ++q) {
      int c = c0 + 4 * j + q;
      float2 cv = cl[c];
      float2 t = twl[(p * c) & 127];
      float v = cv.x * t.x - cv.y * t.y;
      ((unsigned short*)&o)[q] = f2bf(v);
    }
    *reinterpret_cast<ushort4*>(dst + c0 + 4 * j) = o;
  }
  // mask channels 128-133 + zeros 134-143
  if (tid < 128) {
    const int w = tid;
    float v[6];
#pragma unroll
    for (int cm = 0; cm < 6; ++cm)
      v[cm] = maskE[(((size_t)(b * 6 + cm) * 128) + h) * 128 + w];
    unsigned short* d2 = x0 + ((size_t)bh * 128 + w) * 144 + 128;
    ushort4 m0, m1, mz;
    m0.x = f2bf(v[0]); m0.y = f2bf(v[1]); m0.z = f2bf(v[2]); m0.w = f2bf(v[3]);
    m1.x = f2bf(v[4]); m1.y = f2bf(v[5]); m1.z = 0; m1.w = 0;
    mz.x = 0; mz.y = 0; mz.z = 0; mz.w = 0;
    reinterpret_cast<ushort4*>(d2)[0] = m0;
    reinterpret_cast<ushort4*>(d2)[1] = m1;
    reinterpret_cast<ushort4*>(d2)[2] = mz;
    reinterpret_cast<ushort4*>(d2)[3] = mz;
  }
}

// ---------------- weight convert + permute: src[m][ci][t] fp32 -> dst[m][t*CINP+ci] bf16
template<int CIN, int CINP>
__global__ __launch_bounds__(256)
void cvtperm_kernel(const float* __restrict__ src, unsigned short* __restrict__ dst) {
  __shared__ unsigned short tile[16][68];
  const int m = blockIdx.y;
  const int ci0 = blockIdx.x * 64;
  const int tid = threadIdx.x;
  {
    const int ci = ci0 + (tid >> 2);
    const int t0 = (tid & 3) * 4;
    float4 v = make_float4(0.f, 0.f, 0.f, 0.f);
    if (ci < CIN) v = *reinterpret_cast<const float4*>(&src[((size_t)m * CIN + ci) * 16 + t0]);
    const int cr = tid >> 2;
    tile[t0 + 0][cr] = f2bf(v.x);
    tile[t0 + 1][cr] = f2bf(v.y);
    tile[t0 + 2][cr] = f2bf(v.z);
    tile[t0 + 3][cr] = f2bf(v.w);
  }
  __syncthreads();
  {
    const int t = tid >> 4;
    const int co = (tid & 15) * 4;
    const int ci = ci0 + co;
    if (ci < CINP) {
      ushort4 o;
      o.x = tile[t][co]; o.y = tile[t][co + 1]; o.z = tile[t][co + 2]; o.w = tile[t][co + 3];
      *reinterpret_cast<ushort4*>(&dst[(size_t)m * (16 * CINP) + (size_t)t * CINP + ci]) = o;
    }
  }
}

// ---------------- channels-last conv, 128x128 tile, LDS dbuf + depth-2 reg prefetch --
// Champion structure (r18/r20): one barrier per 32-k-step, bf16 partials, XCD swizzle.
template<int CINP, int CSTOR, int COUT, int HI, int WI, int HO, int WO, int NSPLIT, bool FUSED>
__global__ __launch_bounds__(256, 2)
void conv_cl11_kernel(const unsigned short* __restrict__ X,
                      const unsigned short* __restrict__ Wt,
                      const float* __restrict__ bias,
                      unsigned short* __restrict__ Y,
                      unsigned short* __restrict__ P) {
  constexpr int KTOT = 16 * CINP;
  constexpr int CPT = CINP / 32;
  constexpr int NCHT = 16 * CPT;
  constexpr int CPS = NCHT / NSPLIT;
  constexpr int HOWO = HO * WO;
  constexpr int LHW = __builtin_ctz(HOWO);
  constexpr int LWO = __builtin_ctz(WO);
  constexpr size_t PSTRIDE = (size_t)8 * HOWO * COUT;
  constexpr int NIT = CPS;                // 80/64/64/32

  __shared__ __align__(16) unsigned short As[2][128 * 32];
  __shared__ __align__(16) unsigned short Bs[2][128 * 32];

  const int tid = threadIdx.x;
  const int lane = tid & 63;
  const int wv = tid >> 6;
  const int wm = wv >> 1, wn = wv & 1;
  int bxr = blockIdx.x;
  {
    int gx = gridDim.x;
    if ((gx & 7) == 0) bxr = (bxr & 7) * (gx >> 3) + (bxr >> 3);
  }
  const int n0 = bxr * 128;
  const int m0 = blockIdx.y * 128;
  const int split = blockIdx.z;
  const int r = lane & 15, g = lane >> 4;

  const int row0 = tid >> 2;
  const int row1 = row0 + 64;
  const int chk = tid & 3;
  const int lw0 = row0 * 32 + (((chk + ((row0 >> 1) & 3)) & 3) * 8);
  const int lw1 = row1 * 32 + (((chk + ((row1 >> 1) & 3)) & 3) * 8);

  int bb0, bho0, bwo0, bb1, bho1, bwo1;
  {
    int rn0 = n0 + row0, rn1 = n0 + row1;
    bb0 = rn0 >> LHW; bb1 = rn1 >> LHW;
    int re0 = rn0 & (HOWO - 1), re1 = rn1 & (HOWO - 1);
    bho0 = re0 >> LWO; bho1 = re1 >> LWO;
    bwo0 = re0 & (WO - 1); bwo1 = re1 & (WO - 1);
  }

  const int start = split * CPS;
  int tapI = start / CPT, ccI = start % CPT;
  size_t boff0, boff1; bool bok0, bok1;
  auto tap_geom = [&](int t) {
    int kh = t >> 2, kw = t & 3;
    {
      int h = 2 * bho0 - 1 + kh, w = 2 * bwo0 - 1 + kw;
      bool hv = (unsigned)h < (unsigned)HI, wvv = (unsigned)w < (unsigned)WI;
      bok0 = hv && wvv;
      boff0 = (((size_t)bb0 * HI + (hv ? h : 0)) * WI + (wvv ? w : 0)) * (size_t)CSTOR;
    }
    {
      int h = 2 * bho1 - 1 + kh, w = 2 * bwo1 - 1 + kw;
      bool hv = (unsigned)h < (unsigned)HI, wvv = (unsigned)w < (unsigned)WI;
      bok1 = hv && wvv;
      boff1 = (((size_t)bb1 * HI + (hv ? h : 0)) * WI + (wvv ? w : 0)) * (size_t)CSTOR;
    }
  };
  tap_geom(tapI);

  auto issue = [&](uint4& a0r, uint4& a1r, uint4& b0r, uint4& b1r) {
    const int kbase = tapI * CINP + ccI * 32 + chk * 8;
    a0r = *reinterpret_cast<const uint4*>(Wt + (size_t)(m0 + row0) * KTOT + kbase);
    a1r = *reinterpret_cast<const uint4*>(Wt + (size_t)(m0 + row1) * KTOT + kbase);
    int ci = ccI * 32 + chk * 8;
    bool ok0 = bok0, ok1 = bok1;
    int cic = ci;
    if constexpr (CSTOR < CINP) {
      if (ci >= CSTOR) { ok0 = false; ok1 = false; cic = 0; }
    }
    uint4 z = make_uint4(0u, 0u, 0u, 0u);
    uint4 v0 = *reinterpret_cast<const uint4*>(X + boff0 + cic);
    uint4 v1 = *reinterpret_cast<const uint4*>(X + boff1 + cic);
    b0r = ok0 ? v0 : z;
    b1r = ok1 ? v1 : z;
  };
  auto advance = [&]() {
    ccI++;
    if (ccI == CPT) { ccI = 0; tapI++; if (tapI < 16) tap_geom(tapI); }
  };

  uint4 avA0, avA1, bvA0, bvA1;
  uint4 avB0, avB1, bvB0, bvB1;
  issue(avA0, avA1, bvA0, bvA1); advance();
  issue(avB0, avB1, bvB0, bvB1); advance();

  f32x4 acc[4][4] = {};

#define CONV_PHASE(BUF, AV0, AV1, BV0, BV1, HASNEXT)                                    \
  *reinterpret_cast<uint4*>(&As[BUF][lw0]) = AV0;                                       \
  *reinterpret_cast<uint4*>(&As[BUF][lw1]) = AV1;                                       \
  *reinterpret_cast<uint4*>(&Bs[BUF][lw0]) = BV0;                                       \
  *reinterpret_cast<uint4*>(&Bs[BUF][lw1]) = BV1;                                       \
  __syncthreads();                                                                      \
  if (HASNEXT) { issue(AV0, AV1, BV0, BV1); advance(); }                                \
  {                                                                                     \
    bf16x8 af[4], bf[4];                                                                \
    _Pragma("unroll")                                                                   \
    for (int mi = 0; mi < 4; ++mi) {                                                    \
      int rw = wm * 64 + mi * 16 + r;                                                   \
      af[mi] = *reinterpret_cast<const bf16x8*>(                                        \
          &As[BUF][rw * 32 + (((g + ((rw >> 1) & 3)) & 3) * 8)]);                       \
    }                                                                                   \
    _Pragma("unroll")                                                                   \
    for (int ni = 0; ni < 4; ++ni) {                                                    \
      int rw = wn * 64 + ni * 16 + r;                                                   \
      bf[ni] = *reinterpret_cast<const bf16x8*>(                                        \
          &Bs[BUF][rw * 32 + (((g + ((rw >> 1) & 3)) & 3) * 8)]);                       \
    }                                                                                   \
    _Pragma("unroll")                                                                   \
    for (int mi = 0; mi < 4; ++mi)                                                      \
      _Pragma("unroll")                                                                 \
      for (int ni = 0; ni < 4; ++ni)                                                    \
        acc[mi][ni] = __builtin_amdgcn_mfma_f32_16x16x32_bf16(af[mi], bf[ni],           \
                                                              acc[mi][ni], 0, 0, 0);    \
  }

  for (int ii = 0; ii < NIT / 2; ++ii) {
    CONV_PHASE(0, avA0, avA1, bvA0, bvA1, (2 * ii + 2 < NIT))
    CONV_PHASE(1, avB0, avB1, bvB0, bvB1, (2 * ii + 3 < NIT))
  }
#undef CONV_PHASE

  // epilogue: C frag mapping col(n)=lane&15=r, row(m)=g*4+q
#pragma unroll
  for (int ni = 0; ni < 4; ++ni) {
    int n = n0 + wn * 64 + ni * 16 + r;
    int b = n >> LHW;
    int rem = n & (HOWO - 1);
    size_t obase = ((size_t)b * HOWO + rem) * COUT;
#pragma unroll
    for (int mi = 0; mi < 4; ++mi) {
      int mb = m0 + wm * 64 + mi * 16 + g * 4;
      f32x4 a = acc[mi][ni];
      if constexpr (FUSED) {
        float v0 = a[0] + bias[mb + 0]; v0 = v0 > 0.f ? v0 : 0.2f * v0;
        float v1 = a[1] + bias[mb + 1]; v1 = v1 > 0.f ? v1 : 0.2f * v1;
        float v2 = a[2] + bias[mb + 2]; v2 = v2 > 0.f ? v2 : 0.2f * v2;
        float v3 = a[3] + bias[mb + 3]; v3 = v3 > 0.f ? v3 : 0.2f * v3;
        ushort4 o;
        o.x = f2bf(v0); o.y = f2bf(v1); o.z = f2bf(v2); o.w = f2bf(v3);
        *reinterpret_cast<ushort4*>(&Y[obase + mb]) = o;
      } else {
        ushort4 o;
        o.x = f2bf(a[0]); o.y = f2bf(a[1]); o.z = f2bf(a[2]); o.w = f2bf(a[3]);
        *reinterpret_cast<ushort4*>(&P[split * PSTRIDE + obase + mb]) = o;
      }
    }
  }
}

// ---------------- NHWC split-reduce (bf16 partials) + inorm + lrelu (+pool) ---------
template<int HOWO, int COUT, int NSPLIT, bool DOPOOL>
__global__ __launch_bounds__(256)
void inorm_bf_kernel(const unsigned short* __restrict__ P, unsigned short* __restrict__ Y,
                     float* __restrict__ pooled) {
  constexpr int PER = HOWO / 32;
  constexpr size_t PSTRIDE = (size_t)8 * HOWO * COUT;
  const int b = blockIdx.y;
  const int cl = threadIdx.x & 7;
  const int c = blockIdx.x * 8 + cl;
  const int hw0 = threadIdx.x >> 3;   // 0..31
  const unsigned short* base = P + ((size_t)b * HOWO) * COUT + c;
  float v[PER];
  float s1 = 0.f, s2 = 0.f;
#pragma unroll
  for (int j = 0; j < PER; ++j) {
    int hw = hw0 + j * 32;
    float x = 0.f;
#pragma unroll
    for (int s = 0; s < NSPLIT; ++s) x += bf2f(base[s * PSTRIDE + (size_t)hw * COUT]);
    v[j] = x; s1 += x; s2 += x * x;
  }
  __shared__ float r1[32][9], r2[32][9];
  __shared__ float ms[8], rs[8];
  r1[hw0][cl] = s1; r2[hw0][cl] = s2;
  __syncthreads();
  if (threadIdx.x < 8) {
    float a1 = 0.f, a2 = 0.f;
#pragma unroll
    for (int i = 0; i < 32; ++i) { a1 += r1[i][threadIdx.x]; a2 += r2[i][threadIdx.x]; }
    float mean = a1 * (1.0f / HOWO);
    float var = a2 * (1.0f / HOWO) - mean * mean;
    ms[threadIdx.x] = mean;
    rs[threadIdx.x] = rsqrtf(var + 1e-5f);
  }
  __syncthreads();
  const float mean = ms[cl], rstd = rs[cl];
  unsigned short* yb = Y + ((size_t)b * HOWO) * COUT + c;
  float psum = 0.f;
#pragma unroll
  for (int j = 0; j < PER; ++j) {
    int hw = hw0 + j * 32;
    float t = (v[j] - mean) * rstd;
    t = t > 0.f ? t : 0.2f * t;
    if constexpr (DOPOOL) psum += t;
    yb[(size_t)hw * COUT] = f2bf(t);
  }
  if constexpr (DOPOOL) {
    __syncthreads();                // all done reading r1
    r1[hw0][cl] = psum;
    __syncthreads();
    if (threadIdx.x < 8) {
      float a = 0.f;
#pragma unroll
      for (int i = 0; i < 32; ++i) a += r1[i][threadIdx.x];
      pooled[(size_t)b * COUT + blockIdx.x * 8 + threadIdx.x] = a * (1.0f / HOWO);
    }
  }
}

// ---------------- final linear ----------------
__global__ __launch_bounds__(64)
void fc_kernel(const float* __restrict__ pooled, const float* __restrict__ w4,
               const float* __restrict__ b4, float* __restrict__ out) {
  const int bo = blockIdx.x;
  const int b = bo >> 7, o = bo & 127;
  const int lane = threadIdx.x;
  float s = 0.f;
#pragma unroll
  for (int j = 0; j < 16; ++j) {
    int c = lane + j * 64;
    s += pooled[b * 1024 + c] * w4[o * 1024 + c];
  }
#pragma unroll
  for (int off = 32; off > 0; off >>= 1) s += __shfl_xor(s, off);
  if (lane == 0) out[bo] = s + b4[o];
}

extern "C" void kernel_launch(void* const* d_in, const int* in_sizes, int n_in,
                              void* d_out, int out_size, void* d_ws, size_t ws_size,
                              hipStream_t stream) {
  (void)in_sizes; (void)n_in; (void)out_size; (void)ws_size;
  const float* image = (const float*)d_in[0];
  const float* maskE = (const float*)d_in[1];
  const float* w0 = (const float*)d_in[2];
  const float* b0 = (const float*)d_in[3];
  const float* w1 = (const float*)d_in[4];
  const float* w2 = (const float*)d_in[6];
  const float* w3 = (const float*)d_in[8];
  const float* w4 = (const float*)d_in[10];
  const float* b4 = (const float*)d_in[11];
  float* out = (float*)d_out;

  char* ws = (char*)d_ws;
  size_t off = 0;
  auto alloc = [&](size_t bytes) -> void* {
    void* p = ws + off;
    off = (off + bytes + 255) & ~(size_t)255;
    return p;
  };

  const size_t X0BYTES = (size_t)8 * 128 * 128 * 144 * 2;   // 37,748,736
  unsigned short* wbuf = (unsigned short*)alloc((size_t)1024 * 16384 * 2);
  char* bufA = (char*)alloc(X0BYTES + 256);
  char* bufB = (char*)alloc((size_t)8 * 4096 * 256 * 2);
  float* pooled = (float*)alloc(8192 * 4);

  unsigned short* x0 = (unsigned short*)bufA;
  unsigned short* part = (unsigned short*)bufA;
  unsigned short* a0 = (unsigned short*)bufB;
  unsigned short* a1 = (unsigned short*)bufB;
  unsigned short* a2 = (unsigned short*)bufB;
  unsigned short* a3 = (unsigned short*)bufB;

  // fused DFT + spectral map (channels-last)
  sep_cl3_kernel<<<1024, 256, 0, stream>>>(image, maskE, x0);

  // conv0: 134(pad160)->256, fused bias+lrelu, full K. 512 blocks (2/CU).
  cvtperm_kernel<134, 160><<<dim3(3, 256), 256, 0, stream>>>(w0, wbuf);
  conv_cl11_kernel<160, 144, 256, 128, 128, 64, 64, 1, true>
      <<<dim3(256, 2, 1), 256, 0, stream>>>(x0, wbuf, b0, a0, nullptr);

  // conv1: 256->512, split 2. 512 blocks.
  cvtperm_kernel<256, 256><<<dim3(4, 512), 256, 0, stream>>>(w1, wbuf);
  conv_cl11_kernel<256, 256, 512, 64, 64, 32, 32, 2, false>
      <<<dim3(64, 4, 2), 256, 0, stream>>>(a0, wbuf, nullptr, nullptr, part);
  inorm_bf_kernel<1024, 512, 2, false><<<dim3(64, 8), 256, 0, stream>>>(part, a1, nullptr);

  // conv2: 512->1024, split 4. 512 blocks.
  cvtperm_kernel<512, 512><<<dim3(8, 1024), 256, 0, stream>>>(w2, wbuf);
  conv_cl11_kernel<512, 512, 1024, 32, 32, 16, 16, 4, false>
      <<<dim3(16, 8, 4), 256, 0, stream>>>(a1, wbuf, nullptr, nullptr, part);
  inorm_bf_kernel<256, 1024, 4, false><<<dim3(128, 8), 256, 0, stream>>>(part, a2, nullptr);

  // conv3: 1024->1024, split 16. 512 blocks. inorm fuses avg-pool.
  cvtperm_kernel<1024, 1024><<<dim3(16, 1024), 256, 0, stream>>>(w3, wbuf);
  conv_cl11_kernel<1024, 1024, 1024, 16, 16, 8, 8, 16, false>
      <<<dim3(4, 8, 16), 256, 0, stream>>>(a2, wbuf, nullptr, nullptr, part);
  inorm_bf_kernel<64, 1024, 16, true><<<dim3(128, 8), 256, 0, stream>>>(part, a3, pooled);

  // fc
  fc_kernel<<<1024, 64, 0, stream>>>(pooled, w4, b4, out);
}